// Round 1
// baseline (527.438 us; speedup 1.0000x reference)
//
#include <hip/hip_runtime.h>

#define IMG_W 512
#define IMG_H 512
#define HCHUNK 4
#define HSTEP (IMG_H / HCHUNK)  // 128

__global__ void radon_zero(float* __restrict__ out, int n) {
    int i = blockIdx.x * blockDim.x + threadIdx.x;
    if (i < n) out[i] = 0.0f;
}

__global__ __launch_bounds__(256) void radon_kernel(
    const float* __restrict__ x, const float* __restrict__ theta,
    float* __restrict__ out, int N, int A)
{
    int idx = blockIdx.x * blockDim.x + threadIdx.x;
    int w    = idx & (IMG_W - 1);     // w innermost -> lanes sample adjacent parallel lines
    int tmp  = idx >> 9;              // / 512
    int hc   = tmp & (HCHUNK - 1);
    int tmp2 = tmp >> 2;              // / HCHUNK
    int a    = tmp2 % A;
    int n    = tmp2 / A;
    if (n >= N) return;

    // angle -> direction (computed once per thread, amortized over 128 samples)
    float rad = theta[a] * (3.14159265358979323846f / 180.0f);
    float c = cosf(rad);
    float s = sinf(rad);

    // X = linspace(-1,1,512)[w]
    float X = fmaf((float)w, 2.0f / 511.0f, -1.0f);
    // ix(h) = 255.5*(c*X + 1) + s*(h - 255.5); iy(h) = 255.5*(-s*X + 1) + c*(h - 255.5)
    float ixb = 255.5f * fmaf(c, X, 1.0f);
    float iyb = 255.5f * fmaf(-s, X, 1.0f);

    const float* __restrict__ img = x + (size_t)n * (IMG_H * IMG_W);

    float acc = 0.0f;
    int h0 = hc * HSTEP;
    #pragma unroll 4
    for (int h = h0; h < h0 + HSTEP; ++h) {
        float t  = (float)h - 255.5f;          // exact in fp32
        float ix = fmaf(s, t, ixb);
        float iy = fmaf(c, t, iyb);

        float fx0 = floorf(ix);
        float fy0 = floorf(iy);
        float wx1 = ix - fx0;
        float wy1 = iy - fy0;
        float wx0 = 1.0f - wx1;
        float wy0 = 1.0f - wy1;

        int jx0 = (int)fx0;
        int jy0 = (int)fy0;
        int jx1 = jx0 + 1;
        int jy1 = jy0 + 1;

        // zero-pad border: fold validity into weights (unsigned trick handles <0)
        if ((unsigned)jx0 > 511u) wx0 = 0.0f;
        if ((unsigned)jx1 > 511u) wx1 = 0.0f;
        if ((unsigned)jy0 > 511u) wy0 = 0.0f;
        if ((unsigned)jy1 > 511u) wy1 = 0.0f;

        int cx0 = min(max(jx0, 0), 511);
        int cx1 = min(max(jx1, 0), 511);
        int cy0 = min(max(jy0, 0), 511);
        int cy1 = min(max(jy1, 0), 511);

        const float* __restrict__ r0 = img + cy0 * IMG_W;
        const float* __restrict__ r1 = img + cy1 * IMG_W;
        float v00 = r0[cx0];
        float v01 = r0[cx1];
        float v10 = r1[cx0];
        float v11 = r1[cx1];

        acc = fmaf(wy0, fmaf(wx0, v00, wx1 * v01), acc);
        acc = fmaf(wy1, fmaf(wx0, v10, wx1 * v11), acc);
    }

    // out layout: (N, C=1, W, A) -> ((n*W + w)*A + a)
    atomicAdd(&out[(size_t)(n * IMG_W + w) * A + a], acc);
}

extern "C" void kernel_launch(void* const* d_in, const int* in_sizes, int n_in,
                              void* d_out, int out_size, void* d_ws, size_t ws_size,
                              hipStream_t stream) {
    const float* x     = (const float*)d_in[0];
    const float* theta = (const float*)d_in[1];
    float* out = (float*)d_out;

    int A = in_sizes[1];                       // 180
    int N = in_sizes[0] / (IMG_H * IMG_W);     // 2

    int total_out = N * IMG_W * A;             // 184320
    radon_zero<<<(total_out + 255) / 256, 256, 0, stream>>>(out, total_out);

    int total = N * A * HCHUNK * IMG_W;        // 737280
    radon_kernel<<<(total + 255) / 256, 256, 0, stream>>>(x, theta, out, N, A);
}

// Round 2
// 374.939 us; speedup vs baseline: 1.4067x; 1.4067x over previous
//
#include <hip/hip_runtime.h>

#define IMG 512
#define HCHUNK 4
#define HSTEP (IMG / HCHUNK)  // 128

__global__ void radon_zero(float* __restrict__ out, int n) {
    int i = blockIdx.x * blockDim.x + threadIdx.x;
    if (i < n) out[i] = 0.0f;
}

// LDS-tiled transpose: xt[n][i][j] = x[n][j][i]
__global__ __launch_bounds__(256) void transpose_kernel(
    const float* __restrict__ x, float* __restrict__ xt)
{
    __shared__ float tile[32][33];
    int n  = blockIdx.z;
    int bx = blockIdx.x * 32, by = blockIdx.y * 32;
    int tx = threadIdx.x, ty = threadIdx.y;  // block = (32, 8)
    const float* src = x  + (size_t)n * IMG * IMG;
    float*       dst = xt + (size_t)n * IMG * IMG;
    #pragma unroll
    for (int i = 0; i < 32; i += 8)
        tile[ty + i][tx] = src[(size_t)(by + ty + i) * IMG + bx + tx];
    __syncthreads();
    #pragma unroll
    for (int i = 0; i < 32; i += 8)
        dst[(size_t)(bx + ty + i) * IMG + by + tx] = tile[tx][ty + i];
}

__global__ __launch_bounds__(256) void radon_kernel(
    const float* __restrict__ x, const float* __restrict__ xt,
    const float* __restrict__ theta, float* __restrict__ out, int N, int A)
{
    int idx  = blockIdx.x * blockDim.x + threadIdx.x;
    int w    = idx & (IMG - 1);       // w innermost: lanes sample adjacent parallel lines
    int tmp  = idx >> 9;              // / 512
    int hc   = tmp & (HCHUNK - 1);
    int tmp2 = tmp >> 2;
    int a    = tmp2 % A;
    int n    = tmp2 / A;
    if (n >= N) return;

    float rad = theta[a] * (3.14159265358979323846f / 180.0f);
    float c = cosf(rad);
    float s = sinf(rad);

    // X = linspace(-1,1,512)[w];  255.5*(2/511) == 1.0 exactly
    float X   = fmaf((float)w, 2.0f / 511.0f, -1.0f);
    float ixb = 255.5f * fmaf(c, X, 1.0f);   // ix(h) = s*(h-255.5) + ixb
    float iyb = 255.5f * fmaf(-s, X, 1.0f);  // iy(h) = c*(h-255.5) + iyb

    // For steep angles (|s|>|c|) the across-lane step is mostly in y ->
    // 64 lanes would hit 64 different rows. Sample the transposed image
    // with ix/iy swapped instead: x[iy][ix] == xt[ix][iy]. The weight and
    // border logic is symmetric under the swap.
    bool steep = fabsf(s) > fabsf(c);
    const float* __restrict__ img = (steep ? xt : x) + (size_t)n * (IMG * IMG);
    float sx = steep ? c   : s,  bx = steep ? iyb : ixb;
    float sy = steep ? s   : c,  by = steep ? ixb : iyb;

    float acc = 0.0f;
    int h0 = hc * HSTEP;
    #pragma unroll 8
    for (int h = h0; h < h0 + HSTEP; ++h) {
        float t  = (float)h - 255.5f;          // exact in fp32
        float ix = fmaf(sx, t, bx);
        float iy = fmaf(sy, t, by);

        float fx0 = floorf(ix);
        float fy0 = floorf(iy);
        float wx1 = ix - fx0;
        float wy1 = iy - fy0;
        float wx0 = 1.0f - wx1;
        float wy0 = 1.0f - wy1;

        int jx0 = (int)fx0;
        int jy0 = (int)fy0;
        int jx1 = jx0 + 1;
        int jy1 = jy0 + 1;

        // zero-pad border: fold validity into weights
        if ((unsigned)jx0 > 511u) wx0 = 0.0f;
        if ((unsigned)jx1 > 511u) wx1 = 0.0f;
        if ((unsigned)jy0 > 511u) wy0 = 0.0f;
        if ((unsigned)jy1 > 511u) wy1 = 0.0f;

        int cx0 = min(max(jx0, 0), 511);
        int cx1 = min(max(jx1, 0), 511);
        int cy0 = min(max(jy0, 0), 511);
        int cy1 = min(max(jy1, 0), 511);

        const float* __restrict__ r0 = img + cy0 * IMG;
        const float* __restrict__ r1 = img + cy1 * IMG;
        float v00 = r0[cx0];
        float v01 = r0[cx1];
        float v10 = r1[cx0];
        float v11 = r1[cx1];

        acc = fmaf(wy0, fmaf(wx0, v00, wx1 * v01), acc);
        acc = fmaf(wy1, fmaf(wx0, v10, wx1 * v11), acc);
    }

    // out layout: (N, C=1, W, A) -> ((n*W + w)*A + a)
    atomicAdd(&out[(size_t)(n * IMG + w) * A + a], acc);
}

extern "C" void kernel_launch(void* const* d_in, const int* in_sizes, int n_in,
                              void* d_out, int out_size, void* d_ws, size_t ws_size,
                              hipStream_t stream) {
    const float* x     = (const float*)d_in[0];
    const float* theta = (const float*)d_in[1];
    float* out = (float*)d_out;
    float* xt  = (float*)d_ws;                 // 2 * 512 * 512 * 4 B = 2 MB

    int A = in_sizes[1];                       // 180
    int N = in_sizes[0] / (IMG * IMG);         // 2

    int total_out = N * IMG * A;               // 184320
    radon_zero<<<(total_out + 255) / 256, 256, 0, stream>>>(out, total_out);

    dim3 tb(32, 8);
    dim3 tg(IMG / 32, IMG / 32, N);
    transpose_kernel<<<tg, tb, 0, stream>>>(x, xt);

    int total = N * A * HCHUNK * IMG;          // 737280
    radon_kernel<<<(total + 255) / 256, 256, 0, stream>>>(x, xt, theta, out, N, A);
}

// Round 4
// 219.872 us; speedup vs baseline: 2.3988x; 1.7053x over previous
//
#include <hip/hip_runtime.h>

#define IMG 512
#define WT 64     // w-tile (lanes)
#define HT 128    // h-tile per workgroup
#define NT 512    // threads per workgroup (8 waves)
#define HC (NT / WT)      // 8 h-chunks
#define HPER (HT / HC)    // 16 samples per thread
#define TILE_FLOATS 20480 // 80 KB -> 2 WG/CU; worst case (ny+1)*pitch ~= 19800

__global__ void radon_zero(float* __restrict__ out, int n) {
    int i = blockIdx.x * blockDim.x + threadIdx.x;
    if (i < n) out[i] = 0.0f;
}

__global__ __launch_bounds__(NT) void radon_lds(
    const float* __restrict__ x, const float* __restrict__ theta,
    float* __restrict__ out, int N, int A)
{
    __shared__ float tile[TILE_FLOATS];
    int a  = blockIdx.z % A;
    int n  = blockIdx.z / A;
    int w0 = blockIdx.x * WT;
    int h0 = blockIdx.y * HT;

    float rad = theta[a] * (3.14159265358979323846f / 180.0f);
    float c = cosf(rad), s = sinf(rad);

    // Sample coords (exact: 255.5*(2/511) == 1):
    //   ix(w,h) =  c*(w-255.5) + s*(h-255.5) + 255.5
    //   iy(w,h) = -s*(w-255.5) + c*(h-255.5) + 255.5
    float u0 = (float)w0 - 255.5f, u1 = u0 + (float)(WT - 1);
    float t0 = (float)h0 - 255.5f, t1 = t0 + (float)(HT - 1);

    float cu0 = c * u0, cu1 = c * u1, st0 = s * t0, st1 = s * t1;
    float su0 = s * u0, su1 = s * u1, ct0 = c * t0, ct1 = c * t1;

    float ixmin = fminf(fminf(cu0 + st0, cu0 + st1), fminf(cu1 + st0, cu1 + st1)) + 255.5f;
    float ixmax = fmaxf(fmaxf(cu0 + st0, cu0 + st1), fmaxf(cu1 + st0, cu1 + st1)) + 255.5f;
    float iymin = fminf(fminf(ct0 - su0, ct0 - su1), fminf(ct1 - su0, ct1 - su1)) + 255.5f;
    float iymax = fmaxf(fmaxf(ct0 - su0, ct0 - su1), fmaxf(ct1 - su0, ct1 - su1)) + 255.5f;

    // bbox with safety margin; +1 col/row for the bilinear +1 tap
    int xmin = (int)floorf(ixmin) - 1;
    int xmax = (int)floorf(ixmax) + 1;
    int ymin = (int)floorf(iymin) - 1;
    int ymax = (int)floorf(iymax) + 1;

    int ox  = max(xmin, 0);
    int xhi = min(xmax + 1, IMG - 1);
    int oy  = max(ymin, 0);
    int yhi = min(ymax + 1, IMG - 1);
    int wx  = xhi - ox + 1;
    int ny  = yhi - oy + 1;
    if (wx <= 0 || ny <= 0) return;   // tile entirely outside image (WG-uniform)

    int pitch = (wx + 1) | 1;         // >= wx+1 and odd (bank-conflict-free rows)

    // ---- stage bbox into LDS, zero-padding cols [wx,pitch) and row ny ----
    // Every location the sample loop can read is initialized (NaN-safe).
    const float* __restrict__ img = x + (size_t)n * (IMG * IMG);
    int lane = threadIdx.x & 63;
    int wv   = threadIdx.x >> 6;      // 8 waves
    for (int yy = wv; yy < ny; yy += HC) {
        const float* __restrict__ src = img + (size_t)(oy + yy) * IMG + ox;
        float* __restrict__ dst = tile + yy * pitch;
        for (int xx = lane; xx < pitch; xx += 64)
            dst[xx] = (xx < wx) ? src[xx] : 0.0f;
    }
    for (int xx = threadIdx.x; xx < pitch; xx += NT)
        tile[ny * pitch + xx] = 0.0f;
    __syncthreads();

    bool interior = (xmin >= 0) && (xmax + 1 <= IMG - 1) &&
                    (ymin >= 0) && (ymax + 1 <= IMG - 1);

    // ---- compute ----
    int w = w0 + lane;
    float u   = (float)w - 255.5f;
    float fxb = fmaf(c,  u, 255.5f - (float)ox);  // + s*t per sample (local coords)
    float fyb = fmaf(-s, u, 255.5f - (float)oy);  // + c*t per sample

    int wxm1 = wx - 1;
    int nym1 = ny - 1;
    int hstart = h0 + wv * HPER;

    float acc = 0.0f;
    if (interior) {
        // all 4 taps of every sample are valid image texels inside the bbox
        #pragma unroll
        for (int i = 0; i < HPER; ++i) {
            float t  = (float)(hstart + i) - 255.5f;
            float fx = fmaf(s, t, fxb);   // >= 1 in interior tiles
            float fy = fmaf(c, t, fyb);
            int jx = (int)fx;             // trunc == floor (nonneg)
            int jy = (int)fy;
            float wx1 = fx - (float)jx;
            float wy1 = fy - (float)jy;
            float wx0 = 1.0f - wx1, wy0 = 1.0f - wy1;

            const float* __restrict__ p0 = tile + (jy * pitch + jx);
            float v00 = p0[0];
            float v01 = p0[1];
            float v10 = p0[pitch];
            float v11 = p0[pitch + 1];

            acc = fmaf(wy0, fmaf(wx1, v01, wx0 * v00), acc);
            acc = fmaf(wy1, fmaf(wx1, v11, wx0 * v10), acc);
        }
    } else {
        #pragma unroll
        for (int i = 0; i < HPER; ++i) {
            float t  = (float)(hstart + i) - 255.5f;
            float fx = fmaf(s, t, fxb);
            float fy = fmaf(c, t, fyb);

            float flx = floorf(fx), fly = floorf(fy);
            float wx1 = fx - flx,   wy1 = fy - fly;
            float wx0 = 1.0f - wx1, wy0 = 1.0f - wy1;

            int jx = (int)flx, jy = (int)fly;
            int gx = jx + ox,  gy = jy + oy;   // global coords of the floor tap

            // zero-pad border, keeping the fixed pair-read valid:
            //  gx == -1: the x1 tap (global col 0) sits in local slot 0.
            //  gx == 511: slot+1 is the zero-filled pad column.
            float nwx0 = ((unsigned)gx <= 511u) ? wx0 : ((gx == -1) ? wx1 : 0.0f);
            float nwx1 = ((unsigned)gx <= 510u) ? wx1 : 0.0f;
            float nwy0 = ((unsigned)gy <= 511u) ? wy0 : ((gy == -1) ? wy1 : 0.0f);
            float nwy1 = ((unsigned)gy <= 510u) ? wy1 : 0.0f;

            int lx = min(max(jx, 0), wxm1);
            int ly = min(max(jy, 0), nym1);

            const float* __restrict__ p0 = tile + (ly * pitch + lx);
            float v00 = p0[0];
            float v01 = p0[1];          // col lx+1 <= wx: staged or zero pad
            float v10 = p0[pitch];      // row ly+1 <= ny: staged or zero row
            float v11 = p0[pitch + 1];

            acc = fmaf(nwy0, fmaf(nwx1, v01, nwx0 * v00), acc);
            acc = fmaf(nwy1, fmaf(nwx1, v11, nwx0 * v10), acc);
        }
    }

    // ---- reduce the HC partials per w, one atomic per (w, h-tile) ----
    __syncthreads();                 // all tile reads done
    tile[threadIdx.x] = acc;
    __syncthreads();
    if (threadIdx.x < WT) {
        float r = 0.0f;
        #pragma unroll
        for (int k = 0; k < HC; ++k) r += tile[k * WT + threadIdx.x];
        atomicAdd(&out[((size_t)n * IMG + w0 + threadIdx.x) * A + a], r);
    }
}

extern "C" void kernel_launch(void* const* d_in, const int* in_sizes, int n_in,
                              void* d_out, int out_size, void* d_ws, size_t ws_size,
                              hipStream_t stream) {
    const float* x     = (const float*)d_in[0];
    const float* theta = (const float*)d_in[1];
    float* out = (float*)d_out;

    int A = in_sizes[1];                   // 180
    int N = in_sizes[0] / (IMG * IMG);     // 2

    int total_out = N * IMG * A;           // 184320
    radon_zero<<<(total_out + 255) / 256, 256, 0, stream>>>(out, total_out);

    dim3 grid(IMG / WT, IMG / HT, N * A);  // 8 x 4 x 360
    radon_lds<<<grid, NT, 0, stream>>>(x, theta, out, N, A);
}